// Round 1
// baseline (307.223 us; speedup 1.0000x reference)
//
#include <hip/hip_runtime.h>
#include <hip/hip_bf16.h>

// ViT attention, MFMA bf16 pipeline. B=16, N=1024, C=768, H=12, D=64.
// Round 6: attention restructure.
//  - S^T = K*Q^T (not Q*K^T): lane's 4 C-regs = 4 consecutive KEYS for one q
//    -> P round-trip writes are 8x ds_write_b64 instead of 32x ds_write_b16.
//  - double-buffered K/Vt staging via global_load_lds: 1 barrier/tile, DMA
//    for tile k+1 overlaps compute of tile k.
//  - XCD-aware block swizzle: 8 q-tile blocks sharing one (b,h)'s K/Vt land
//    consecutively on the SAME XCD (bid%8 round-robin) -> L2 reuse.
//  - SCALE folded into Q at gemm1 epilogue (cols<768 scaled by 0.125).
// gemm: 128x128 tile, BK=64, global_load_lds w=16, XOR-8 chunk swizzle
// (round-5 validated). gemm1 writes V transposed into vt directly.
// ws: xb[25.2M]|qk[50.3M]|vt[25.2M]|wqkv[3.5M]|wproj[1.2M] = 105.4 MB.
// MFMA 16x16x32 bf16 layouts (m89/m91):
//   A-op: lane(quad,l16) holds A[m=l16][k=quad*8+j]
//   B-op: lane holds B[k=quad*8+j][n=l16]   (same per-lane pattern as A-op)
//   C/D : reg r = D[row=quad*4+r][col=l16]

typedef __attribute__((ext_vector_type(8))) short short8;
typedef __attribute__((ext_vector_type(4))) float floatx4;

constexpr int Bsz = 16, Nseq = 1024, Cdim = 768, Hh = 12, Dd = 64;
constexpr float SCALE = 0.125f;  // 64^-0.5, folded into Q at gemm1

__device__ __forceinline__ ushort f2bs(float f) {
    union { __hip_bfloat16 h; ushort u; } cv;
    cv.h = __float2bfloat16(f);
    return cv.u;
}
__device__ __forceinline__ void stF(float* p, float v) { *p = v; }
__device__ __forceinline__ void stF(ushort* p, float v) { *p = f2bs(v); }

// async 16B/lane global->LDS DMA. lds must be wave-uniform; HW adds lane*16.
__device__ __forceinline__ void gld16(void* lds, const void* g) {
    __builtin_amdgcn_global_load_lds(
        (const __attribute__((address_space(1))) unsigned int*)g,
        (__attribute__((address_space(3))) unsigned int*)lds, 16, 0, 0);
}

// fp32 -> bf16 pack: x | qkv_w | proj_w
__global__ __launch_bounds__(256) void pack_bf16(
        const float* __restrict__ x, const float* __restrict__ w1,
        const float* __restrict__ w2, ushort* __restrict__ xb,
        ushort* __restrict__ w1b, ushort* __restrict__ w2b) {
    const size_t n0 = (size_t)Bsz * Nseq * Cdim;   // 12,582,912
    const size_t n1 = (size_t)3 * Cdim * Cdim;     //  1,769,472
    size_t i = ((size_t)blockIdx.x * 256 + threadIdx.x) * 4;
    const float* src;
    ushort* dst;
    if (i < n0) { src = x; dst = xb; }
    else if (i < n0 + n1) { i -= n0; src = w1; dst = w1b; }
    else { i -= n0 + n1; src = w2; dst = w2b; }
    float4 v = *(const float4*)&src[i];
    *(ushort4*)&dst[i] = make_ushort4(f2bs(v.x), f2bs(v.y), f2bs(v.z), f2bs(v.w));
}

// C = A[M,K] @ Bw[N,K]^T + bias[N]. 128x128 tile, BK=64, 256 thr, 4 waves.
// Cols >= split written transposed to vt when vmode (per-head V^T).
// Cols < qsplit scaled by qscale (SCALE folding for Q).
template <typename TO>
__global__ __launch_bounds__(256) void gemm_nt_mfma(
        const ushort* __restrict__ A, const ushort* __restrict__ Bw,
        const float* __restrict__ bias, TO* __restrict__ C0,
        ushort* __restrict__ vt, int split, int ld0,
        int M, int N, int K, int vmode, int qsplit, float qscale) {
    __shared__ ushort As[128 * 64];   // [row][k] unpadded, XOR-8 swizzled
    __shared__ ushort Bs[128 * 64];
    const int t = threadIdx.x;
    const int lane = t & 63;
    const int w = t >> 6;
    const int quad = lane >> 4;
    const int l16 = lane & 15;
    const int m0 = blockIdx.y * 128;
    const int n0 = blockIdx.x * 128;
    const int mw = (w >> 1) * 64;
    const int nw = (w & 1) * 64;
    const int srow = lane >> 3;
    const int schunk = lane & 7;

    floatx4 acc[4][4];
#pragma unroll
    for (int i = 0; i < 4; ++i)
#pragma unroll
        for (int j = 0; j < 4; ++j) acc[i][j] = (floatx4)0.0f;

    for (int k0 = 0; k0 < K; k0 += 64) {
        __syncthreads();
#pragma unroll
        for (int i = 0; i < 4; ++i) {
            int r0 = (w * 4 + i) * 8;
            int row = r0 + srow;
            int cs = (schunk ^ (row & 7)) * 8;
            gld16(&As[r0 * 64], &A[(size_t)(m0 + row) * K + k0 + cs]);
            gld16(&Bs[r0 * 64], &Bw[(size_t)(n0 + row) * K + k0 + cs]);
        }
        __syncthreads();

#pragma unroll
        for (int kk = 0; kk < 2; ++kk) {
            const int pc = ((kk * 4 + quad) ^ (l16 & 7)) * 8;
            short8 af[4], bfr[4];
#pragma unroll
            for (int i = 0; i < 4; ++i)
                af[i] = *(const short8*)&As[(mw + i * 16 + l16) * 64 + pc];
#pragma unroll
            for (int j = 0; j < 4; ++j)
                bfr[j] = *(const short8*)&Bs[(nw + j * 16 + l16) * 64 + pc];
#pragma unroll
            for (int i = 0; i < 4; ++i)
#pragma unroll
                for (int j = 0; j < 4; ++j)
                    acc[i][j] = __builtin_amdgcn_mfma_f32_16x16x32_bf16(
                        af[i], bfr[j], acc[i][j], 0, 0, 0);
        }
    }

#pragma unroll
    for (int j = 0; j < 4; ++j) {
        int col = n0 + nw + j * 16 + l16;
        float bc = bias[col];
        float sc = (col < qsplit) ? qscale : 1.0f;
        if (vmode && col >= split) {
            int ch = col - split;
            int h = ch >> 6, d = ch & 63;
#pragma unroll
            for (int i = 0; i < 4; ++i)
#pragma unroll
                for (int r = 0; r < 4; ++r) {
                    int row = m0 + mw + i * 16 + quad * 4 + r;
                    int b = row >> 10, n = row & 1023;
                    vt[(((size_t)(b * Hh + h)) * Dd + d) * Nseq + n] =
                        f2bs(acc[i][j][r] + bc);
                }
        } else {
#pragma unroll
            for (int i = 0; i < 4; ++i)
#pragma unroll
                for (int r = 0; r < 4; ++r) {
                    int row = m0 + mw + i * 16 + quad * 4 + r;
                    stF(&C0[(size_t)row * ld0 + col], (acc[i][j][r] + bc) * sc);
                }
        }
    }
}

// Flash attention, no-max softmax, S^T formulation.
// Block = (b,h, 128-q tile), 4 waves; wave w owns q rows w*32..w*32+31.
// KV tiles of 64, double-buffered staging.
__global__ __launch_bounds__(256) void attn_mfma(const ushort* __restrict__ qk,
                                                 const ushort* __restrict__ vt,
                                                 ushort* __restrict__ outp) {
    __shared__ ushort Ks[2][64 * 64];   // [key][d], XOR-8 swizzled
    __shared__ ushort Vts[2][64 * 64];  // [d][key], XOR-8 swizzled
    __shared__ ushort Ps[4][32][72];    // per-wave P[q][key], 144B rows

    const int t = threadIdx.x;
    const int lane = t & 63;
    const int w = t >> 6;
    const int quad = lane >> 4;
    const int l16 = lane & 15;
    const int srow = lane >> 3;
    const int schunk = lane & 7;

    // XCD swizzle: 8 q-tiles of one bh land on one XCD, consecutively.
    const int bid = blockIdx.x;
    const int qt = (bid >> 3) & 7;
    const int bh = (bid & 7) + 8 * (bid >> 6);
    const int h = bh % Hh, b = bh / Hh;

    const size_t rs = 2 * Cdim;  // 1536
    const ushort* qbase = qk + (size_t)b * Nseq * rs + h * Dd;
    const ushort* kbase = qbase + Cdim;
    const ushort* vbase = vt + (size_t)bh * Dd * Nseq;

    // Q fragments in registers (pre-scaled by SCALE at gemm1)
    short8 aq[2][2];
#pragma unroll
    for (int qn = 0; qn < 2; ++qn)
#pragma unroll
        for (int kc = 0; kc < 2; ++kc) {
            int q = qt * 128 + w * 32 + qn * 16 + l16;
            aq[qn][kc] = *(const short8*)&qbase[(size_t)q * rs + kc * 32 + quad * 8];
        }

    auto stage = [&](int kt64, int buf) {
#pragma unroll
        for (int i = 0; i < 2; ++i) {
            int r0 = (w * 2 + i) * 8;
            int row = r0 + srow;
            int cs = (schunk ^ (row & 7)) * 8;
            gld16(&Ks[buf][r0 * 64], &kbase[(size_t)(kt64 * 64 + row) * rs + cs]);
            gld16(&Vts[buf][r0 * 64], &vbase[(size_t)row * Nseq + kt64 * 64 + cs]);
        }
    };

    floatx4 o[2][4];
    float lsum[2] = {0.f, 0.f};
#pragma unroll
    for (int mt = 0; mt < 2; ++mt)
#pragma unroll
        for (int dt = 0; dt < 4; ++dt) o[mt][dt] = (floatx4)0.0f;

    stage(0, 0);
    for (int kt = 0; kt < Nseq / 64; ++kt) {
        __syncthreads();  // drains DMA for tile kt; guards buf reuse
        if (kt + 1 < Nseq / 64) stage(kt + 1, (kt + 1) & 1);
        const ushort* Kb = Ks[kt & 1];
        const ushort* Vb = Vts[kt & 1];

        // S^T = K Q^T : C-layout reg r = S^T[key=km*16+quad*4+r][q=qn*16+l16]
        floatx4 st[4][2];
#pragma unroll
        for (int km = 0; km < 4; ++km)
#pragma unroll
            for (int qn = 0; qn < 2; ++qn) st[km][qn] = (floatx4)0.0f;
#pragma unroll
        for (int kc = 0; kc < 2; ++kc) {
            const int pc = ((kc * 4 + quad) ^ (l16 & 7)) * 8;
            short8 ak[4];
#pragma unroll
            for (int km = 0; km < 4; ++km)
                ak[km] = *(const short8*)&Kb[(km * 16 + l16) * 64 + pc];
#pragma unroll
            for (int km = 0; km < 4; ++km)
#pragma unroll
                for (int qn = 0; qn < 2; ++qn)
                    st[km][qn] = __builtin_amdgcn_mfma_f32_16x16x32_bf16(
                        ak[km], aq[qn][kc], st[km][qn], 0, 0, 0);
        }

        // p = exp(s); lane's 4 regs = 4 consecutive keys -> one b64 write
#pragma unroll
        for (int km = 0; km < 4; ++km)
#pragma unroll
            for (int qn = 0; qn < 2; ++qn) {
                float p0 = __expf(st[km][qn][0]);
                float p1 = __expf(st[km][qn][1]);
                float p2 = __expf(st[km][qn][2]);
                float p3 = __expf(st[km][qn][3]);
                lsum[qn] += (p0 + p1) + (p2 + p3);
                uint2 pk;
                pk.x = (uint)f2bs(p0) | ((uint)f2bs(p1) << 16);
                pk.y = (uint)f2bs(p2) | ((uint)f2bs(p3) << 16);
                *(uint2*)&Ps[w][qn * 16 + l16][km * 16 + quad * 4] = pk;
            }

        // O += P V
#pragma unroll
        for (int kc = 0; kc < 2; ++kc) {
            const int pcv = ((kc * 4 + quad) ^ (l16 & 7)) * 8;
            short8 ap[2];
#pragma unroll
            for (int mt = 0; mt < 2; ++mt)
                ap[mt] = *(const short8*)&Ps[w][mt * 16 + l16][kc * 32 + quad * 8];
#pragma unroll
            for (int dt = 0; dt < 4; ++dt) {
                short8 bv = *(const short8*)&Vb[(dt * 16 + l16) * 64 + pcv];
#pragma unroll
                for (int mt = 0; mt < 2; ++mt)
                    o[mt][dt] = __builtin_amdgcn_mfma_f32_16x16x32_bf16(
                        ap[mt], bv, o[mt][dt], 0, 0, 0);
            }
        }
    }

    // lsum[qn] holds keys {km*16+quad*4+r} for q=qn*16+l16: reduce over quads
#pragma unroll
    for (int qn = 0; qn < 2; ++qn) {
        float v = lsum[qn];
        v += __shfl_xor(v, 16);
        v += __shfl_xor(v, 32);
        lsum[qn] = v;
    }
    // o rows are q = mt*16+quad*4+r; fetch matching l from lane l16=quad*4+r
#pragma unroll
    for (int mt = 0; mt < 2; ++mt)
#pragma unroll
        for (int dt = 0; dt < 4; ++dt)
#pragma unroll
            for (int r = 0; r < 4; ++r) {
                float li = __shfl(lsum[mt], quad * 4 + r);
                int q = qt * 128 + w * 32 + mt * 16 + quad * 4 + r;
                int d = dt * 16 + l16;
                outp[((size_t)(b * Nseq + q)) * Cdim + h * Dd + d] =
                    f2bs(o[mt][dt][r] / li);
            }
}

extern "C" void kernel_launch(void* const* d_in, const int* in_sizes, int n_in,
                              void* d_out, int out_size, void* d_ws, size_t ws_size,
                              hipStream_t stream) {
    const float* x      = (const float*)d_in[0];
    const float* qkv_w  = (const float*)d_in[1];
    const float* qkv_b  = (const float*)d_in[2];
    const float* proj_w = (const float*)d_in[3];
    const float* proj_b = (const float*)d_in[4];
    float* out = (float*)d_out;

    const int M = Bsz * Nseq;  // 16384
    ushort* xb    = (ushort*)d_ws;                        // [16384x768]
    ushort* qk    = xb + (size_t)M * Cdim;                // [16384x1536]
    ushort* vtbuf = qk + (size_t)M * 2 * Cdim;            // [192][64][1024]
    ushort* wqkvb = vtbuf + (size_t)Hh * Bsz * Dd * Nseq; // [2304x768]
    ushort* wprjb = wqkvb + (size_t)3 * Cdim * Cdim;      // [768x768]
    ushort* attnout = xb;  // xb dead after gemm1

    // 0) fp32 -> bf16 pack
    pack_bf16<<<14592, 256, 0, stream>>>(x, qkv_w, proj_w, xb, wqkvb, wprjb);
    // 1) qkv GEMM: Q (cols<768, pre-scaled by SCALE) + K -> qk; V -> vt^T
    gemm_nt_mfma<ushort><<<dim3(18, 128), 256, 0, stream>>>(
        xb, wqkvb, qkv_b, qk, vtbuf, 2 * Cdim, 2 * Cdim, M, 3 * Cdim, Cdim, 1,
        Cdim, SCALE);
    // 2) attention
    attn_mfma<<<Bsz * Hh * (Nseq / 128), 256, 0, stream>>>(qk, vtbuf, attnout);
    // 3) projection -> fp32 out
    gemm_nt_mfma<float><<<dim3(6, 128), 256, 0, stream>>>(
        attnout, wprjb, proj_b, out, vtbuf, 1 << 30, Cdim, M, Cdim, Cdim, 0,
        0, 1.0f);
}